// Round 4
// baseline (1159.021 us; speedup 1.0000x reference)
//
#include <hip/hip_runtime.h>
#include <hip/hip_bf16.h>

#define D 128
#define NP 16          // src-range sub-buckets (slices) per dst; slice = 2MB of hin
#define DPB 64         // dst per coarse bucket (b = d>>6)
#define KPB (DPB * NP) // fine keys per bucket = 1024
#define SUB 64         // sub-cursors per bucket
#define CAP_SUB 64     // staging capacity per (sub, bucket); mean 16
#define NPG 8          // nodes per 16-lane group in k_layer
#define NBLK 128       // nodes per block in k_layer (16 groups * NPG)

typedef __attribute__((ext_vector_type(8))) __bf16 bf16x8;
typedef __attribute__((ext_vector_type(4))) float f32x4;
typedef __attribute__((ext_vector_type(4))) short s16x4;
typedef __attribute__((ext_vector_type(8))) short s16x8;

static __device__ __forceinline__ short f2bf(float f) {
    union { float f; unsigned u; } in; in.f = f;
    unsigned u = in.u;
    u += 0x7fffu + ((u >> 16) & 1u);   // round-to-nearest-even
    return (short)(u >> 16);
}

// ---- phase 1: coarse-bucket edges; 100K sub-cursors kill contention ----
// pack: fineKey(10b: (d&63)*16 + (src>>13)) << 17 | src(17b)   [N < 2^17]
__global__ void k_bucket(const int* __restrict__ src, const int* __restrict__ dst,
                         int* __restrict__ bcnt, int* __restrict__ staging,
                         int E, int KBE) {
    int i = blockIdx.x * 256 + threadIdx.x;
    if (i >= E) return;
    int d = dst[i], s = src[i];
    int b = d >> 6;
    int key = ((d & 63) << 4) | (s >> 13);   // 16 src-slices of 8192 nodes (2MB)
    int j = blockIdx.x & (SUB - 1);          // j%8 == heuristic XCD
    int slot = atomicAdd(&bcnt[j * KBE + b], 1);
    if (slot < CAP_SUB) staging[((size_t)j * KBE + b) * CAP_SUB + slot] = (key << 17) | s;
}

// ---- per-bucket totals (parallel, coalesced per-j stripes) ----
__global__ void k_btot(const int* __restrict__ bcnt, int* __restrict__ btot, int KBE) {
    int b = blockIdx.x * 256 + threadIdx.x;
    if (b >= KBE) return;
    int v = 0;
    #pragma unroll
    for (int j = 0; j < SUB; j++) {
        int c = bcnt[j * KBE + b];
        v += (c > CAP_SUB) ? CAP_SUB : c;
    }
    btot[b] = v;
}

// ---- exclusive scan of bucket totals (single block, chunked) ----
__global__ void k_bscan(const int* __restrict__ btot, int* __restrict__ bbase,
                        int* __restrict__ row_ptr, int nkeys, int KBE) {
    __shared__ int sm[512];
    __shared__ int carry;
    int t = threadIdx.x;
    if (t == 0) carry = 0;
    __syncthreads();
    for (int c0 = 0; c0 < KBE; c0 += 512) {
        int b = c0 + t;
        int v = (b < KBE) ? btot[b] : 0;
        sm[t] = v;
        __syncthreads();
        for (int off = 1; off < 512; off <<= 1) {
            int x = (t >= off) ? sm[t - off] : 0;
            __syncthreads();
            sm[t] += x;
            __syncthreads();
        }
        if (b < KBE) bbase[b] = sm[t] - v + carry;
        __syncthreads();
        if (t == 0) carry += sm[511];
        __syncthreads();
    }
    if (t == 0) { bbase[KBE] = carry; row_ptr[nkeys] = carry; }
}

// ---- phase 2: per-bucket fine CSR build in LDS ----
__global__ __launch_bounds__(256) void k_build(
    const int* __restrict__ staging, const int* __restrict__ bcnt,
    const int* __restrict__ bbase, int* __restrict__ row_ptr,
    int* __restrict__ csr_src, float* __restrict__ dinv, int N, int KBE)
{
    const int b = blockIdx.x;
    const int tid = threadIdx.x;
    __shared__ int cnt[KPB];          // 4 KB at NP=16
    __shared__ int subn[SUB];
    __shared__ int chunkbuf[256];
    __shared__ int carry;

    if (tid < SUB) {
        int c = bcnt[tid * KBE + b];
        subn[tid] = (c > CAP_SUB) ? CAP_SUB : c;
    }
    for (int k = tid; k < KPB; k += 256) cnt[k] = 0;
    if (tid == 0) carry = 0;
    __syncthreads();

    const int base = bbase[b];
    const int nb = bbase[b + 1] - base;          // bucket total (from scan)
    const int j = tid >> 2, l4 = tid & 3;
    const int* __restrict__ sreg = staging + ((size_t)j * KBE + b) * CAP_SUB;
    const int sn = subn[j];

    // histogram over fine keys
    for (int e = l4; e < sn; e += 4)
        atomicAdd(&cnt[sreg[e] >> 17], 1);
    __syncthreads();

    // in-place exclusive scan of cnt[0..KPB)  (4 chunks of 256)
    #pragma unroll 1
    for (int c = 0; c < KPB / 256; c++) {
        int idx = c * 256 + tid;
        int v = cnt[idx];
        chunkbuf[tid] = v;
        __syncthreads();
        for (int off = 1; off < 256; off <<= 1) {
            int x = (tid >= off) ? chunkbuf[tid - off] : 0;
            __syncthreads();
            chunkbuf[tid] += x;
            __syncthreads();
        }
        cnt[idx] = chunkbuf[tid] - v + carry;
        __syncthreads();
        if (tid == 255) carry += chunkbuf[255];
        __syncthreads();
    }

    for (int k = tid; k < KPB; k += 256)
        row_ptr[(size_t)b * KPB + k] = base + cnt[k];
    for (int dl = tid; dl < DPB; dl += 256) {
        int d = b * DPB + dl;
        if (d < N) {
            int hi2 = (dl == DPB - 1) ? nb : cnt[(dl + 1) * NP];
            int deg = hi2 - cnt[dl * NP];
            dinv[d] = rsqrtf((float)deg + 1.0f);
        }
    }
    __syncthreads();

    // scatter into this bucket's contiguous csr region (LDS cursors)
    for (int e = l4; e < sn; e += 4) {
        int w = sreg[e];
        int slot = base + atomicAdd(&cnt[w >> 17], 1);
        csr_src[slot] = w & 0x1FFFF;
    }
}

// ---- batch is SORTED: segment starts AND counts via binary search ----
__global__ void k_gseg(const int* __restrict__ batch, int* __restrict__ gstart,
                       int* __restrict__ gcnt, int N, int B) {
    int g = blockIdx.x * blockDim.x + threadIdx.x;
    if (g > B) return;
    int lo = 0, hi = N;
    while (lo < hi) {
        int mid = (lo + hi) >> 1;
        if (batch[mid] < g) lo = mid + 1; else hi = mid;
    }
    gstart[g] = lo;
    if (g < B) {
        int lo2 = lo, hi2 = N;
        while (lo2 < hi2) {
            int mid = (lo2 + hi2) >> 1;
            if (batch[mid] < g + 1) lo2 = mid + 1; else hi2 = mid;
        }
        gcnt[g] = lo2 - lo;
    }
}

// ---- x' = dinv[i] * x  -> bf16 (pre-scaled feature rows) ----
__global__ void k_cvt_x(const float* __restrict__ x, const float* __restrict__ dinv,
                        short* __restrict__ xb, int total4) {
    int i = blockIdx.x * blockDim.x + threadIdx.x;
    if (i < total4) {
        float d = dinv[i >> 5];
        float4 v = ((const float4*)x)[i];
        s16x4 o;
        o.x = f2bf(v.x * d); o.y = f2bf(v.y * d);
        o.z = f2bf(v.z * d); o.w = f2bf(v.w * d);
        ((s16x4*)xb)[i] = o;
    }
}

// ---- conv_w: fp32 [L][k][n] -> bf16 transposed [L][n][k] ----
__global__ void k_cvt_w(const float* __restrict__ W, short* __restrict__ Wt, int total) {
    int i = blockIdx.x * blockDim.x + threadIdx.x;
    if (i < total) {
        int l = i >> 14;
        int rem = i & 16383;
        int n = rem >> 7;
        int k = rem & 127;
        Wt[i] = f2bf(W[(l << 14) + (k << 7) + n]);
    }
}

// ---- FUSED layer v8: SLICE-PHASED gathering, 128 nodes/block ----
// Theory: gathers were L2-miss bound (hin 25.6MB vs 4MB L2/XCD, random).
// Now: grid = 782 blocks, ~768 co-resident (41KB LDS -> 3 blocks/CU) ->
// single scheduling generation. All blocks walk the 16 src-slices (2MB
// each) IN PHASE: at any instant the global gather footprint is ~1-2
// slices, which fits every XCD's L2 -> gathers become L2 hits.
// Each 16-lane group owns 8 nodes (acc[8][8] fp32 in registers); per
// slice it round-robins one edge per node per pass -> 8 gathers in
// flight, all indices compile-time static (no scratch).
// Edge order per node: slices ascending, then csr order == previous
// kernel's order (summation tree differs: sequential, fp32).
// mode 0: hout[r] = bf16( relu(C + b) * dinv[r] );  mode 1: hrelu = fp32 relu(C+b)
__global__ __launch_bounds__(256, 3) void k_layer(
    const short* __restrict__ hin, const int* __restrict__ row_ptr,
    const int* __restrict__ csr_src, const float* __restrict__ dinv,
    const short* __restrict__ Wt, const float* __restrict__ bias,
    short* __restrict__ hout, float* __restrict__ hrelu, int N, int nkeys, int mode)
{
    __shared__ __align__(16) short tile[NBLK * 128];   // 32 KB, swizzled 16B chunks
    __shared__ int rp[NBLK * NP + 1];                  // 8.2 KB row_ptr slice
    const int tid = threadIdx.x;
    const int wave = tid >> 6;
    const int lane = tid & 63;
    const int group = lane >> 4;
    const int gidx = wave * 4 + group;       // 0..15: group index in block
    const int lg = lane & 15;
    const int off = lg * 8;
    const int node_base = blockIdx.x * NBLK;

    // ---- stage this block's row_ptr range (coalesced; clamp at nkeys) ----
    {
        const int base_k = node_base * NP;
        for (int k = tid; k < NBLK * NP + 1; k += 256) {
            int gi = base_k + k;
            rp[k] = row_ptr[(gi <= nkeys) ? gi : nkeys];
        }
    }
    __syncthreads();

    // ---- phase 1: slice-phased aggregation; group owns nodes ln0..ln0+7 ----
    const int ln0 = gidx * NPG;
    float acc[NPG][8];
    #pragma unroll
    for (int n = 0; n < NPG; n++) {
        int i = node_base + ln0 + n;
        if (i < N) {
            bf16x8 v = *(const bf16x8*)(hin + (size_t)i * D + off);
            #pragma unroll
            for (int k = 0; k < 8; k++) acc[n][k] = (float)v[k];
        } else {
            #pragma unroll
            for (int k = 0; k < 8; k++) acc[n][k] = 0.f;
        }
    }

    #pragma unroll 1
    for (int s = 0; s < NP; s++) {
        int ts[NPG], es[NPG];
        #pragma unroll
        for (int n = 0; n < NPG; n++) {
            ts[n] = rp[(ln0 + n) * NP + s];
            es[n] = rp[(ln0 + n) * NP + s + 1];
        }
        for (;;) {
            bool a[NPG];
            bool any = false;
            #pragma unroll
            for (int n = 0; n < NPG; n++) { a[n] = ts[n] < es[n]; any |= a[n]; }
            if (!__any((int)any)) break;
            int idx[NPG];
            #pragma unroll
            for (int n = 0; n < NPG; n++) if (a[n]) idx[n] = csr_src[ts[n]];
            bf16x8 v[NPG];
            #pragma unroll
            for (int n = 0; n < NPG; n++) if (a[n])
                v[n] = *(const bf16x8*)(hin + (size_t)idx[n] * D + off);
            #pragma unroll
            for (int n = 0; n < NPG; n++) if (a[n]) {
                #pragma unroll
                for (int k = 0; k < 8; k++) acc[n][k] += (float)v[n][k];
                ts[n]++;
            }
        }
    }

    // ---- scale + store tile rows (swizzled) ----
    #pragma unroll
    for (int n = 0; n < NPG; n++) {
        const int ln = ln0 + n;
        const int i = node_base + ln;
        s16x8 o;
        if (i < N) {
            const float di = dinv[i];
            #pragma unroll
            for (int k = 0; k < 8; k++) o[k] = f2bf(acc[n][k] * di);
        } else {
            #pragma unroll
            for (int k = 0; k < 8; k++) o[k] = 0;
        }
        *(s16x8*)(&tile[ln * 128 + ((lg ^ (ln & 7)) << 3)]) = o;
    }
    __syncthreads();

    // ---- phase 2: GEMM; wave w computes rows [w*32, w*32+32) x all 128 cols ----
    bf16x8 aa[2][4];
    #pragma unroll
    for (int rt = 0; rt < 2; rt++)
        #pragma unroll
        for (int kt = 0; kt < 4; kt++) {
            const int R = wave * 32 + rt * 16 + lg;
            aa[rt][kt] = *(const bf16x8*)(&tile[R * 128 + (((group + 4 * kt) ^ (R & 7)) << 3)]);
        }

    f32x4 c2[2][8];
    #pragma unroll
    for (int rt = 0; rt < 2; rt++)
        #pragma unroll
        for (int ct = 0; ct < 8; ct++) { f32x4 z = {0.f, 0.f, 0.f, 0.f}; c2[rt][ct] = z; }

    #pragma unroll
    for (int ct = 0; ct < 8; ct++) {
        const short* bp = Wt + (size_t)(ct * 16 + lg) * D + group * 8;
        #pragma unroll
        for (int kt = 0; kt < 4; kt++) {
            bf16x8 b = *(const bf16x8*)(bp + kt * 32);
            #pragma unroll
            for (int rt = 0; rt < 2; rt++)
                c2[rt][ct] = __builtin_amdgcn_mfma_f32_16x16x32_bf16(aa[rt][kt], b, c2[rt][ct], 0, 0, 0);
        }
    }

    // C/D layout: col = lane&15, row = (lane>>4)*4 + reg
    float bcol[8];
    #pragma unroll
    for (int ct = 0; ct < 8; ct++) bcol[ct] = bias[ct * 16 + lg];
    #pragma unroll
    for (int rt = 0; rt < 2; rt++) {
        const int row0 = node_base + wave * 32 + rt * 16 + group * 4;
        #pragma unroll
        for (int i2 = 0; i2 < 4; i2++) {
            const int r2 = row0 + i2;
            if (r2 < N) {
                if (mode == 0) {
                    const float dr = dinv[r2];
                    #pragma unroll
                    for (int ct = 0; ct < 8; ct++) {
                        float val = fmaxf(c2[rt][ct][i2] + bcol[ct], 0.0f);
                        hout[(size_t)r2 * D + ct * 16 + lg] = f2bf(val * dr);
                    }
                } else {
                    #pragma unroll
                    for (int ct = 0; ct < 8; ct++) {
                        hrelu[(size_t)r2 * D + ct * 16 + lg] =
                            fmaxf(c2[rt][ct][i2] + bcol[ct], 0.0f);
                    }
                }
            }
        }
    }
}

// ---- segmented pooling, 4-way row-split per graph for latency hiding ----
__global__ __launch_bounds__(256) void k_pool(const float* __restrict__ hrelu,
                                              const int* __restrict__ gstart,
                                              const int* __restrict__ gcnt,
                                              float* __restrict__ pmax,
                                              float* __restrict__ psum, int B) {
    int g = blockIdx.x >> 2;
    int q = blockIdx.x & 3;
    int c = threadIdx.x & 127;
    int p = threadIdx.x >> 7;
    int start = gstart[g];
    int endr = start + gcnt[g];

    float mx0 = 0.f, mx1 = 0.f, sm0 = 0.f, sm1 = 0.f;
    int r = start + q * 2 + p;
    for (; r + 8 < endr; r += 16) {
        float v0 = hrelu[(size_t)r * D + c];
        float v1 = hrelu[(size_t)(r + 8) * D + c];
        mx0 = fmaxf(mx0, v0); sm0 += v0;
        mx1 = fmaxf(mx1, v1); sm1 += v1;
    }
    if (r < endr) {
        float v0 = hrelu[(size_t)r * D + c];
        mx0 = fmaxf(mx0, v0); sm0 += v0;
    }
    float mx = fmaxf(mx0, mx1), sm = sm0 + sm1;

    __shared__ float smx[128], ssm[128];
    if (p == 1) { smx[c] = mx; ssm[c] = sm; }
    __syncthreads();
    if (p == 0) {
        pmax[((size_t)q * B + g) * D + c] = fmaxf(mx, smx[c]);
        psum[((size_t)q * B + g) * D + c] = sm + ssm[c];
    }
}

// ---- final: combine 4 partials; out[g] = [gmax, gsum/cnt, gsum] @ out_w + out_b ----
__global__ void k_final(const float* __restrict__ pmax, const float* __restrict__ psum,
                        const int* __restrict__ gcnt, const float* __restrict__ ow,
                        const float* __restrict__ ob, float* __restrict__ out, int B) {
    int g = blockIdx.x;
    int t = threadIdx.x;  // 64
    float part[10];
    #pragma unroll
    for (int o = 0; o < 10; o++) part[o] = 0.f;
    float invc = 1.0f / fmaxf((float)gcnt[g], 1.0f);
    for (int k = t; k < 3 * D; k += 64) {
        int c = (k < D) ? k : ((k < 2 * D) ? k - D : k - 2 * D);
        float pk;
        if (k < D) {
            float m = pmax[(size_t)g * D + c];
            #pragma unroll
            for (int q = 1; q < 4; q++) m = fmaxf(m, pmax[((size_t)q * B + g) * D + c]);
            pk = m;
        } else {
            float s = psum[(size_t)g * D + c];
            #pragma unroll
            for (int q = 1; q < 4; q++) s += psum[((size_t)q * B + g) * D + c];
            pk = (k < 2 * D) ? s * invc : s;
        }
        const float* w = ow + k * 10;
        #pragma unroll
        for (int o = 0; o < 10; o++) part[o] += pk * w[o];
    }
    #pragma unroll
    for (int off = 32; off > 0; off >>= 1)
        #pragma unroll
        for (int o = 0; o < 10; o++) part[o] += __shfl_down(part[o], off, 64);
    if (t == 0)
        #pragma unroll
        for (int o = 0; o < 10; o++) out[g * 10 + o] = part[o] + ob[o];
}

extern "C" void kernel_launch(void* const* d_in, const int* in_sizes, int n_in,
                              void* d_out, int out_size, void* d_ws, size_t ws_size,
                              hipStream_t stream) {
    const float* x     = (const float*)d_in[0];
    const int*   ei    = (const int*)d_in[1];
    const int*   batch = (const int*)d_in[2];
    const float* convw = (const float*)d_in[3];
    const float* convb = (const float*)d_in[4];
    const float* outw  = (const float*)d_in[5];
    const float* outb  = (const float*)d_in[6];
    float* out = (float*)d_out;

    const int N = in_sizes[0] / D;        // 100000
    const int E = in_sizes[1] / 2;        // 1600000
    const int L = in_sizes[3] / (D * D);  // 3
    const int B = out_size / 10;          // 256

    const int* src = ei;
    const int* dst = ei + E;

    const int KBE   = (N + DPB - 1) / DPB;     // coarse buckets (1563)
    const int nkeys = KBE * KPB;               // global fine-key space (1.6M)

    char* p = (char*)d_ws;
    auto alloc = [&](size_t bytes) { char* r = p; p += (bytes + 255) & ~255ull; return r; };
    short* hb0     = (short*)alloc((size_t)N * D * 2);      // ping-pong bf16 rows
    short* hb1     = (short*)alloc((size_t)N * D * 2);
    float* hrelu   = (float*)alloc((size_t)N * D * 4);      // fp32 last-layer relu; ALIASED as staging
    short* Wt      = (short*)alloc((size_t)L * D * D * 2);  // bf16 W^T
    int*   row_ptr = (int*)alloc(((size_t)nkeys + 1) * 4);
    int*   csr_src = (int*)alloc((size_t)E * 4);
    int*   bcnt    = (int*)alloc((size_t)SUB * KBE * 4);
    int*   btot    = (int*)alloc((size_t)KBE * 4);
    int*   bbase   = (int*)alloc(((size_t)KBE + 1) * 4);
    float* dinv    = (float*)alloc((size_t)N * 4);
    float* pmax    = (float*)alloc((size_t)4 * B * D * 4);
    float* psum    = (float*)alloc((size_t)4 * B * D * 4);
    int*   gcnt    = (int*)alloc((size_t)B * 4);
    int*   gstart  = (int*)alloc(((size_t)B + 1) * 4);

    // staging: SUB*KBE*CAP_SUB*4 = 64*1563*64*4 = 25.6 MB <= hrelu's 51.2 MB
    int* staging = (int*)hrelu;   // hrelu written only after k_build completes

    hipMemsetAsync(bcnt, 0, (size_t)SUB * KBE * 4, stream);

    k_bucket<<<(E + 255) / 256, 256, 0, stream>>>(src, dst, bcnt, staging, E, KBE);
    k_gseg<<<1, 512, 0, stream>>>(batch, gstart, gcnt, N, B);
    k_btot<<<(KBE + 255) / 256, 256, 0, stream>>>(bcnt, btot, KBE);
    k_bscan<<<1, 512, 0, stream>>>(btot, bbase, row_ptr, nkeys, KBE);
    k_build<<<KBE, 256, 0, stream>>>(staging, bcnt, bbase, row_ptr, csr_src, dinv, N, KBE);
    k_cvt_x<<<((N * D / 4) + 255) / 256, 256, 0, stream>>>(x, dinv, hb0, N * D / 4);
    k_cvt_w<<<((L * D * D) + 255) / 256, 256, 0, stream>>>(convw, Wt, L * D * D);

    const int lblocks = (N + NBLK - 1) / NBLK;   // 782 blocks, ~768 co-resident
    // layer 0: hb0 -> hb1 ; layer 1: hb1 -> hb0 ; layer 2: hb0 -> hrelu
    k_layer<<<lblocks, 256, 0, stream>>>(hb0, row_ptr, csr_src, dinv, Wt,
                                         convb, hb1, hrelu, N, nkeys, 0);
    k_layer<<<lblocks, 256, 0, stream>>>(hb1, row_ptr, csr_src, dinv, Wt + D * D,
                                         convb + D, hb0, hrelu, N, nkeys, 0);
    k_layer<<<lblocks, 256, 0, stream>>>(hb0, row_ptr, csr_src, dinv, Wt + 2 * D * D,
                                         convb + 2 * D, hb1, hrelu, N, nkeys, 1);

    k_pool<<<B * 4, 256, 0, stream>>>(hrelu, gstart, gcnt, pmax, psum, B);
    k_final<<<B, 64, 0, stream>>>(pmax, psum, gcnt, outw, outb, out, B);
}

// Round 5
// 520.315 us; speedup vs baseline: 2.2275x; 2.2275x over previous
//
#include <hip/hip_runtime.h>
#include <hip/hip_bf16.h>

#define D 128
#define NP 8           // src-range sub-buckets (slices) per dst; slice = 3.2MB of hin
#define DPB 64         // dst per coarse bucket (b = d>>6)
#define KPB (DPB * NP) // fine keys per bucket = 512
#define SUB 64         // sub-cursors per bucket
#define CAP_SUB 64     // staging capacity per (sub, bucket); mean 16
#define DSUB 64        // sub-cursors per degree bin (counting sort)
#define NBLK 64        // nodes per k_layer block (4 rounds x 16 groups)

typedef __attribute__((ext_vector_type(8))) __bf16 bf16x8;
typedef __attribute__((ext_vector_type(4))) float f32x4;
typedef __attribute__((ext_vector_type(4))) short s16x4;
typedef __attribute__((ext_vector_type(8))) short s16x8;

static __device__ __forceinline__ short f2bf(float f) {
    union { float f; unsigned u; } in; in.f = f;
    unsigned u = in.u;
    u += 0x7fffu + ((u >> 16) & 1u);   // round-to-nearest-even
    return (short)(u >> 16);
}

// ---- phase 1: coarse-bucket edges; 100K sub-cursors kill contention ----
// pack: fineKey(9b: (d&63)*8 + (src>>14)) << 17 | src(17b)   [N < 2^17]
__global__ void k_bucket(const int* __restrict__ src, const int* __restrict__ dst,
                         int* __restrict__ bcnt, int* __restrict__ staging,
                         int E, int KBE) {
    int i = blockIdx.x * 256 + threadIdx.x;
    if (i >= E) return;
    int d = dst[i], s = src[i];
    int b = d >> 6;
    int key = ((d & 63) << 3) | (s >> 14);
    int j = blockIdx.x & (SUB - 1);      // j%8 == heuristic XCD
    int slot = atomicAdd(&bcnt[j * KBE + b], 1);
    if (slot < CAP_SUB) staging[((size_t)j * KBE + b) * CAP_SUB + slot] = (key << 17) | s;
}

// ---- per-bucket totals (parallel, coalesced per-j stripes) ----
__global__ void k_btot(const int* __restrict__ bcnt, int* __restrict__ btot, int KBE) {
    int b = blockIdx.x * 256 + threadIdx.x;
    if (b >= KBE) return;
    int v = 0;
    #pragma unroll
    for (int j = 0; j < SUB; j++) {
        int c = bcnt[j * KBE + b];
        v += (c > CAP_SUB) ? CAP_SUB : c;
    }
    btot[b] = v;
}

// ---- exclusive scan of bucket totals (single block, chunked) ----
__global__ void k_bscan(const int* __restrict__ btot, int* __restrict__ bbase,
                        int* __restrict__ row_ptr, int nkeys, int KBE) {
    __shared__ int sm[512];
    __shared__ int carry;
    int t = threadIdx.x;
    if (t == 0) carry = 0;
    __syncthreads();
    for (int c0 = 0; c0 < KBE; c0 += 512) {
        int b = c0 + t;
        int v = (b < KBE) ? btot[b] : 0;
        sm[t] = v;
        __syncthreads();
        for (int off = 1; off < 512; off <<= 1) {
            int x = (t >= off) ? sm[t - off] : 0;
            __syncthreads();
            sm[t] += x;
            __syncthreads();
        }
        if (b < KBE) bbase[b] = sm[t] - v + carry;
        __syncthreads();
        if (t == 0) carry += sm[511];
        __syncthreads();
    }
    if (t == 0) { bbase[KBE] = carry; row_ptr[nkeys] = carry; }
}

// ---- phase 2: per-bucket fine CSR build in LDS; also emits degree + histogram ----
__global__ __launch_bounds__(256) void k_build(
    const int* __restrict__ staging, const int* __restrict__ bcnt,
    const int* __restrict__ bbase, int* __restrict__ row_ptr,
    int* __restrict__ csr_src, float* __restrict__ dinv,
    int* __restrict__ deg_arr, int* __restrict__ dsub, int N, int KBE)
{
    const int b = blockIdx.x;
    const int tid = threadIdx.x;
    __shared__ int cnt[KPB];
    __shared__ int subn[SUB];
    __shared__ int chunkbuf[256];
    __shared__ int carry;

    if (tid < SUB) {
        int c = bcnt[tid * KBE + b];
        subn[tid] = (c > CAP_SUB) ? CAP_SUB : c;
    }
    for (int k = tid; k < KPB; k += 256) cnt[k] = 0;
    if (tid == 0) carry = 0;
    __syncthreads();

    const int base = bbase[b];
    const int nb = bbase[b + 1] - base;          // bucket total (from scan)
    const int j = tid >> 2, l4 = tid & 3;
    const int* __restrict__ sreg = staging + ((size_t)j * KBE + b) * CAP_SUB;
    const int sn = subn[j];

    // histogram over fine keys
    for (int e = l4; e < sn; e += 4)
        atomicAdd(&cnt[sreg[e] >> 17], 1);
    __syncthreads();

    // in-place exclusive scan of cnt[0..KPB)  (2 chunks of 256)
    #pragma unroll 1
    for (int c = 0; c < KPB / 256; c++) {
        int idx = c * 256 + tid;
        int v = cnt[idx];
        chunkbuf[tid] = v;
        __syncthreads();
        for (int off = 1; off < 256; off <<= 1) {
            int x = (tid >= off) ? chunkbuf[tid - off] : 0;
            __syncthreads();
            chunkbuf[tid] += x;
            __syncthreads();
        }
        cnt[idx] = chunkbuf[tid] - v + carry;
        __syncthreads();
        if (tid == 255) carry += chunkbuf[255];
        __syncthreads();
    }

    for (int k = tid; k < KPB; k += 256)
        row_ptr[(size_t)b * KPB + k] = base + cnt[k];
    for (int dl = tid; dl < DPB; dl += 256) {
        int d = b * DPB + dl;
        if (d < N) {
            int hi2 = (dl == DPB - 1) ? nb : cnt[(dl + 1) * NP];
            int deg = hi2 - cnt[dl * NP];
            dinv[d] = rsqrtf((float)deg + 1.0f);
            int dc = (deg > 255) ? 255 : deg;
            deg_arr[d] = dc;
            atomicAdd(&dsub[((b & (DSUB - 1)) << 8) + dc], 1);
        }
    }
    __syncthreads();

    // scatter into this bucket's contiguous csr region (LDS cursors)
    for (int e = l4; e < sn; e += 4) {
        int w = sreg[e];
        int slot = base + atomicAdd(&cnt[w >> 17], 1);
        csr_src[slot] = w & 0x1FFFF;
    }
}

// ---- counting-sort scan: 256 threads, thread d owns degree bin d ----
__global__ void k_dscan(const int* __restrict__ dsub, int* __restrict__ dcur) {
    __shared__ int sm[256];
    const int d = threadIdx.x;
    int tot = 0;
    for (int jj = 0; jj < DSUB; jj++) tot += dsub[(jj << 8) + d];
    sm[d] = tot;
    __syncthreads();
    for (int off = 1; off < 256; off <<= 1) {
        int x = (d >= off) ? sm[d - off] : 0;
        __syncthreads();
        sm[d] += x;
        __syncthreads();
    }
    int run = sm[d] - tot;      // exclusive bin base == global rank base
    for (int jj = 0; jj < DSUB; jj++) {
        dcur[(jj << 8) + d] = run;
        run += dsub[(jj << 8) + d];
    }
}

// ---- counting-sort scatter with INTERLEAVED block assignment ----
// global degree-rank r -> block r%LB, slot r/LB. All blocks' slot-q nodes
// share one narrow degree band -> all concurrent rounds walk src slices
// in lockstep (the phase-alignment that makes gathers L2-resident).
__global__ void k_dscat(const int* __restrict__ deg_arr, int* __restrict__ dcur,
                        int* __restrict__ perm, int N, int LB) {
    int i = blockIdx.x * 256 + threadIdx.x;
    if (i >= N) return;
    int dc = deg_arr[i];
    int jj = (i >> 6) & (DSUB - 1);
    int pos = atomicAdd(&dcur[(jj << 8) + dc], 1);   // global rank
    int blk = pos % LB;
    int q = pos / LB;                                 // 0..63
    perm[blk * NBLK + q] = i;
}

// ---- batch is SORTED: segment starts AND counts via binary search ----
__global__ void k_gseg(const int* __restrict__ batch, int* __restrict__ gstart,
                       int* __restrict__ gcnt, int N, int B) {
    int g = blockIdx.x * blockDim.x + threadIdx.x;
    if (g > B) return;
    int lo = 0, hi = N;
    while (lo < hi) {
        int mid = (lo + hi) >> 1;
        if (batch[mid] < g) lo = mid + 1; else hi = mid;
    }
    gstart[g] = lo;
    if (g < B) {
        int lo2 = lo, hi2 = N;
        while (lo2 < hi2) {
            int mid = (lo2 + hi2) >> 1;
            if (batch[mid] < g + 1) lo2 = mid + 1; else hi2 = mid;
        }
        gcnt[g] = lo2 - lo;
    }
}

// ---- x' = dinv[i] * x  -> bf16 (pre-scaled feature rows) ----
__global__ void k_cvt_x(const float* __restrict__ x, const float* __restrict__ dinv,
                        short* __restrict__ xb, int total4) {
    int i = blockIdx.x * blockDim.x + threadIdx.x;
    if (i < total4) {
        float d = dinv[i >> 5];
        float4 v = ((const float4*)x)[i];
        s16x4 o;
        o.x = f2bf(v.x * d); o.y = f2bf(v.y * d);
        o.z = f2bf(v.z * d); o.w = f2bf(v.w * d);
        ((s16x4*)xb)[i] = o;
    }
}

// ---- conv_w: fp32 [L][k][n] -> bf16 transposed [L][n][k] ----
__global__ void k_cvt_w(const float* __restrict__ W, short* __restrict__ Wt, int total) {
    int i = blockIdx.x * blockDim.x + threadIdx.x;
    if (i < total) {
        int l = i >> 14;
        int rem = i & 16383;
        int n = rem >> 7;
        int k = rem & 127;
        Wt[i] = f2bf(W[(l << 14) + (k << 7) + n]);
    }
}

// ---- FUSED layer v9: single-generation, rank-interleaved, r0 inner loop ----
// 64 nodes/block via 4 sequential rounds of the round-0 16-node phase-1
// (exact same dense 4-deep gather chains, register accumulators). 16KB LDS
// + launch_bounds(256,8) (VGPR<=64) -> 8 blocks/CU -> all 1563 blocks
// co-resident (capacity 2048): ONE generation, no tail. perm supplies
// round j with nodes from one global degree band, so all concurrent walks
// sit in the same src slice at the same time -> gathers hit L2.
// mode 0: hout[n] = bf16( relu(C + b) * dinv[n] );  mode 1: hrelu = fp32 relu(C+b)
__global__ __launch_bounds__(256, 8) void k_layer(
    const short* __restrict__ hin, const int* __restrict__ row_ptr,
    const int* __restrict__ csr_src, const float* __restrict__ dinv,
    const int* __restrict__ perm,
    const short* __restrict__ Wt, const float* __restrict__ bias,
    short* __restrict__ hout, float* __restrict__ hrelu, int N, int mode)
{
    __shared__ __align__(16) short tile[NBLK * 128];   // 16 KB, swizzled 16B chunks
    const int tid = threadIdx.x;
    const int wave = tid >> 6;
    const int lane = tid & 63;
    const int group = lane >> 4;
    const int lg = lane & 15;
    const int off = lg * 8;
    const int gidx = wave * 4 + group;       // 0..15
    const int base_ti = blockIdx.x * NBLK;

    // ---- phase 1: 4 rounds x 16 concurrent nodes (one per group) ----
    #pragma unroll 1
    for (int rd = 0; rd < 4; rd++) {
        const int ln = rd * 16 + gidx;       // tile row / perm slot (0..63)
        const int i = perm[base_ti + ln];    // actual node id; -1 = empty slot
        short* dstp = &tile[ln * 128 + ((lg ^ (ln & 7)) << 3)];
        if (i >= 0) {
            float acc[8];
            bf16x8 v = *(const bf16x8*)(hin + (size_t)i * D + off);
            #pragma unroll
            for (int k = 0; k < 8; k++) acc[k] = (float)v[k];

            int t = row_ptr[i * NP];
            const int end = row_ptr[i * NP + NP];
            for (; t + 4 <= end; t += 4) {   // dense 4-deep chains (r0-proven)
                int i0 = csr_src[t + 0], i1 = csr_src[t + 1];
                int i2 = csr_src[t + 2], i3 = csr_src[t + 3];
                bf16x8 v0 = *(const bf16x8*)(hin + (size_t)i0 * D + off);
                bf16x8 v1 = *(const bf16x8*)(hin + (size_t)i1 * D + off);
                bf16x8 v2 = *(const bf16x8*)(hin + (size_t)i2 * D + off);
                bf16x8 v3 = *(const bf16x8*)(hin + (size_t)i3 * D + off);
                #pragma unroll
                for (int k = 0; k < 8; k++)
                    acc[k] += (((float)v0[k] + (float)v1[k]) + ((float)v2[k] + (float)v3[k]));
            }
            for (; t < end; t++) {           // scalar tail (<=3)
                int i0 = csr_src[t];
                bf16x8 v0 = *(const bf16x8*)(hin + (size_t)i0 * D + off);
                #pragma unroll
                for (int k = 0; k < 8; k++) acc[k] += (float)v0[k];
            }

            const float di = dinv[i];
            s16x8 o;
            #pragma unroll
            for (int k = 0; k < 8; k++) o[k] = f2bf(acc[k] * di);
            *(s16x8*)dstp = o;
        } else {
            s16x8 z = {0, 0, 0, 0, 0, 0, 0, 0};
            *(s16x8*)dstp = z;
        }
    }
    __syncthreads();

    // ---- phase 2: GEMM; wave w computes tile rows [w*16, w*16+16) ----
    bf16x8 aa[4];
    const int R = wave * 16 + lg;
    #pragma unroll
    for (int kt = 0; kt < 4; kt++)
        aa[kt] = *(const bf16x8*)(&tile[R * 128 + (((group + 4 * kt) ^ (R & 7)) << 3)]);

    #pragma unroll 1
    for (int half = 0; half < 2; half++) {   // 2 col-halves keep VGPR <= 64
        f32x4 acc2[4];
        #pragma unroll
        for (int ct = 0; ct < 4; ct++) { f32x4 z = {0.f, 0.f, 0.f, 0.f}; acc2[ct] = z; }
        #pragma unroll
        for (int ct = 0; ct < 4; ct++) {
            const short* bp = Wt + (size_t)((half * 4 + ct) * 16 + lg) * D + group * 8;
            #pragma unroll
            for (int kt = 0; kt < 4; kt++) {
                bf16x8 b = *(const bf16x8*)(bp + kt * 32);
                acc2[ct] = __builtin_amdgcn_mfma_f32_16x16x32_bf16(aa[kt], b, acc2[ct], 0, 0, 0);
            }
        }
        float bcol[4];
        #pragma unroll
        for (int ct = 0; ct < 4; ct++) bcol[ct] = bias[(half * 4 + ct) * 16 + lg];

        // C/D layout: col = lane&15, row = (lane>>4)*4 + reg
        #pragma unroll
        for (int i2 = 0; i2 < 4; i2++) {
            const int lrow = wave * 16 + group * 4 + i2;
            const int n2 = perm[base_ti + lrow];
            if (n2 >= 0) {
                if (mode == 0) {
                    const float dr = dinv[n2];
                    #pragma unroll
                    for (int ct = 0; ct < 4; ct++) {
                        float val = fmaxf(acc2[ct][i2] + bcol[ct], 0.0f);
                        hout[(size_t)n2 * D + (half * 4 + ct) * 16 + lg] = f2bf(val * dr);
                    }
                } else {
                    #pragma unroll
                    for (int ct = 0; ct < 4; ct++) {
                        hrelu[(size_t)n2 * D + (half * 4 + ct) * 16 + lg] =
                            fmaxf(acc2[ct][i2] + bcol[ct], 0.0f);
                    }
                }
            }
        }
    }
}

// ---- segmented pooling, 4-way row-split per graph for latency hiding ----
__global__ __launch_bounds__(256) void k_pool(const float* __restrict__ hrelu,
                                              const int* __restrict__ gstart,
                                              const int* __restrict__ gcnt,
                                              float* __restrict__ pmax,
                                              float* __restrict__ psum, int B) {
    int g = blockIdx.x >> 2;
    int q = blockIdx.x & 3;
    int c = threadIdx.x & 127;
    int p = threadIdx.x >> 7;
    int start = gstart[g];
    int endr = start + gcnt[g];

    float mx0 = 0.f, mx1 = 0.f, sm0 = 0.f, sm1 = 0.f;
    int r = start + q * 2 + p;
    for (; r + 8 < endr; r += 16) {
        float v0 = hrelu[(size_t)r * D + c];
        float v1 = hrelu[(size_t)(r + 8) * D + c];
        mx0 = fmaxf(mx0, v0); sm0 += v0;
        mx1 = fmaxf(mx1, v1); sm1 += v1;
    }
    if (r < endr) {
        float v0 = hrelu[(size_t)r * D + c];
        mx0 = fmaxf(mx0, v0); sm0 += v0;
    }
    float mx = fmaxf(mx0, mx1), sm = sm0 + sm1;

    __shared__ float smx[128], ssm[128];
    if (p == 1) { smx[c] = mx; ssm[c] = sm; }
    __syncthreads();
    if (p == 0) {
        pmax[((size_t)q * B + g) * D + c] = fmaxf(mx, smx[c]);
        psum[((size_t)q * B + g) * D + c] = sm + ssm[c];
    }
}

// ---- final: combine 4 partials; out[g] = [gmax, gsum/cnt, gsum] @ out_w + out_b ----
__global__ void k_final(const float* __restrict__ pmax, const float* __restrict__ psum,
                        const int* __restrict__ gcnt, const float* __restrict__ ow,
                        const float* __restrict__ ob, float* __restrict__ out, int B) {
    int g = blockIdx.x;
    int t = threadIdx.x;  // 64
    float part[10];
    #pragma unroll
    for (int o = 0; o < 10; o++) part[o] = 0.f;
    float invc = 1.0f / fmaxf((float)gcnt[g], 1.0f);
    for (int k = t; k < 3 * D; k += 64) {
        int c = (k < D) ? k : ((k < 2 * D) ? k - D : k - 2 * D);
        float pk;
        if (k < D) {
            float m = pmax[(size_t)g * D + c];
            #pragma unroll
            for (int q = 1; q < 4; q++) m = fmaxf(m, pmax[((size_t)q * B + g) * D + c]);
            pk = m;
        } else {
            float s = psum[(size_t)g * D + c];
            #pragma unroll
            for (int q = 1; q < 4; q++) s += psum[((size_t)q * B + g) * D + c];
            pk = (k < 2 * D) ? s * invc : s;
        }
        const float* w = ow + k * 10;
        #pragma unroll
        for (int o = 0; o < 10; o++) part[o] += pk * w[o];
    }
    #pragma unroll
    for (int off = 32; off > 0; off >>= 1)
        #pragma unroll
        for (int o = 0; o < 10; o++) part[o] += __shfl_down(part[o], off, 64);
    if (t == 0)
        #pragma unroll
        for (int o = 0; o < 10; o++) out[g * 10 + o] = part[o] + ob[o];
}

extern "C" void kernel_launch(void* const* d_in, const int* in_sizes, int n_in,
                              void* d_out, int out_size, void* d_ws, size_t ws_size,
                              hipStream_t stream) {
    const float* x     = (const float*)d_in[0];
    const int*   ei    = (const int*)d_in[1];
    const int*   batch = (const int*)d_in[2];
    const float* convw = (const float*)d_in[3];
    const float* convb = (const float*)d_in[4];
    const float* outw  = (const float*)d_in[5];
    const float* outb  = (const float*)d_in[6];
    float* out = (float*)d_out;

    const int N = in_sizes[0] / D;        // 100000
    const int E = in_sizes[1] / 2;        // 1600000
    const int L = in_sizes[3] / (D * D);  // 3
    const int B = out_size / 10;          // 256

    const int* src = ei;
    const int* dst = ei + E;

    const int KBE   = (N + DPB - 1) / DPB;     // coarse buckets (1563)
    const int nkeys = KBE * KPB;               // global fine-key space
    const int LB    = (N + NBLK - 1) / NBLK;   // k_layer blocks (1563)

    char* p = (char*)d_ws;
    auto alloc = [&](size_t bytes) { char* r = p; p += (bytes + 255) & ~255ull; return r; };
    short* hb0     = (short*)alloc((size_t)N * D * 2);      // ping-pong bf16 rows
    short* hb1     = (short*)alloc((size_t)N * D * 2);
    float* hrelu   = (float*)alloc((size_t)N * D * 4);      // fp32 last-layer relu; ALIASED as staging
    short* Wt      = (short*)alloc((size_t)L * D * D * 2);  // bf16 W^T
    int*   row_ptr = (int*)alloc(((size_t)nkeys + 1) * 4);
    int*   csr_src = (int*)alloc((size_t)E * 4);
    int*   bcnt    = (int*)alloc((size_t)SUB * KBE * 4);
    int*   btot    = (int*)alloc((size_t)KBE * 4);
    int*   bbase   = (int*)alloc(((size_t)KBE + 1) * 4);
    float* dinv    = (float*)alloc((size_t)N * 4);
    float* pmax    = (float*)alloc((size_t)4 * B * D * 4);
    float* psum    = (float*)alloc((size_t)4 * B * D * 4);
    int*   gcnt    = (int*)alloc((size_t)B * 4);
    int*   gstart  = (int*)alloc(((size_t)B + 1) * 4);
    int*   deg_arr = (int*)alloc((size_t)N * 4);            // clamped degree per node
    int*   dsub    = (int*)alloc((size_t)DSUB * 256 * 4);   // degree sub-histograms
    int*   dcur    = (int*)alloc((size_t)DSUB * 256 * 4);   // scan bases / cursors
    int*   perm    = (int*)alloc((size_t)LB * NBLK * 4);    // rank-interleaved node ids

    // staging: SUB*KBE*CAP_SUB*4 = 64*1563*64*4 = 25.6 MB <= hrelu's 51.2 MB
    int* staging = (int*)hrelu;   // hrelu written only after k_build completes

    hipMemsetAsync(bcnt, 0, (size_t)SUB * KBE * 4, stream);
    hipMemsetAsync(dsub, 0, (size_t)DSUB * 256 * 4, stream);
    hipMemsetAsync(perm, 0xFF, (size_t)LB * NBLK * 4, stream);   // -1 sentinels

    k_bucket<<<(E + 255) / 256, 256, 0, stream>>>(src, dst, bcnt, staging, E, KBE);
    k_gseg<<<1, 512, 0, stream>>>(batch, gstart, gcnt, N, B);
    k_btot<<<(KBE + 255) / 256, 256, 0, stream>>>(bcnt, btot, KBE);
    k_bscan<<<1, 512, 0, stream>>>(btot, bbase, row_ptr, nkeys, KBE);
    k_build<<<KBE, 256, 0, stream>>>(staging, bcnt, bbase, row_ptr, csr_src, dinv,
                                     deg_arr, dsub, N, KBE);
    k_dscan<<<1, 256, 0, stream>>>(dsub, dcur);
    k_dscat<<<(N + 255) / 256, 256, 0, stream>>>(deg_arr, dcur, perm, N, LB);
    k_cvt_x<<<((N * D / 4) + 255) / 256, 256, 0, stream>>>(x, dinv, hb0, N * D / 4);
    k_cvt_w<<<((L * D * D) + 255) / 256, 256, 0, stream>>>(convw, Wt, L * D * D);

    // layer 0: hb0 -> hb1 ; layer 1: hb1 -> hb0 ; layer 2: hb0 -> hrelu
    k_layer<<<LB, 256, 0, stream>>>(hb0, row_ptr, csr_src, dinv, perm, Wt,
                                    convb, hb1, hrelu, N, 0);
    k_layer<<<LB, 256, 0, stream>>>(hb1, row_ptr, csr_src, dinv, perm, Wt + D * D,
                                    convb + D, hb0, hrelu, N, 0);
    k_layer<<<LB, 256, 0, stream>>>(hb0, row_ptr, csr_src, dinv, perm, Wt + 2 * D * D,
                                    convb + 2 * D, hb1, hrelu, N, 1);

    k_pool<<<B * 4, 256, 0, stream>>>(hrelu, gstart, gcnt, pmax, psum, B);
    k_final<<<B, 64, 0, stream>>>(pmax, psum, gcnt, outw, outb, out, B);
}